// Round 1
// 707.127 us; speedup vs baseline: 1.0380x; 1.0380x over previous
//
#include <hip/hip_runtime.h>
#include <stdint.h>

// Problem constants (match reference)
#define NB   8
#define NP   16384
#define NG   512      // NUM_GROUPS
#define GS   32       // GROUP_SIZE
#define UPK  512      // UPSCALE_K
#define CTX  256      // CONTEXT

// float32 output layout (flat element offsets):
// groups (8,256,32,4) | centers (8,256,4) | emb_mask (8,256) | point_mask (8,256,32)
#define OFF_CENTERS (NB*CTX*GS*4)            // 262144
#define OFF_EMB     (OFF_CENTERS + NB*CTX*4) // 270336
#define OFF_PMASK   (OFF_EMB + NB*CTX)       // 272384

typedef unsigned long long u64;
typedef unsigned int u32;

// Producer/consumer overlap (R16): FPS emits center g at iteration g, but the
// old 3-kernel pipeline ran ~100us of ball-query AFTER the 627us serial FPS
// with 97% of the chip idle. Fused persistent kernel: blocks 0..7 = FPS
// producers (one per batch, one per XCD), blocks 8..255 = ball-query workers
// (31 per batch, same XCD as their producer via blk%8). Centers published in
// PUB-sized windows as 2 agent-scope u64 atomic stores each; readers spin on
// the sentinel 0xFF..FF ((NaN,NaN) — impossible for finite inputs), so no
// fence is needed on the producer's critical path.
// Deadlock safety: grid == 256 and the 88 KiB LDS footprint hard-caps
// occupancy at 1 block/CU -> all 256 blocks co-resident by construction;
// workers wait only on FPS publishes, FPS blocks wait on nothing external.
#define SENT 0xFFFFFFFFFFFFFFFFull
#define PUB  32       // centers published every PUB fps iterations
#define NWK  31       // worker blocks per batch (8 + 8*31 = 256 = #CUs)

// Monotonic float->uint key (full-range; needed for energies which can be <0)
__device__ __forceinline__ u32 fkey(float f) {
  union { float f; u32 u; } v; v.f = f;
  u32 s = v.u;
  return s ^ ((s & 0x80000000u) ? 0xFFFFFFFFu : 0x80000000u);
}

// Strictly-unfused f32 squared distance, op order = np: ((dx*dx+dy*dy)+dz*dz).
// _rn intrinsics forbid FMA contraction (hipcc defaults -ffp-contract=fast).
// NOTE (R15 post-mortem): the algebraic FMA form broke selection (absmax 2.26).
// This unfused difference form is load-bearing.
__device__ __forceinline__ float dist2(float ax, float ay, float az,
                                       float bx, float by, float bz) {
  float dx = __fsub_rn(ax, bx);
  float dy = __fsub_rn(ay, by);
  float dz = __fsub_rn(az, bz);
  return __fadd_rn(__fadd_rn(__fmul_rn(dx, dx), __fmul_rn(dy, dy)),
                   __fmul_rn(dz, dz));
}

// u64 max-combine with a DPP-moved copy (bound_ctrl=false keeps own value
// for invalid sources -> max no-op there). Proven since R8 (absmax 0).
template<int CTRL, int RM>
__device__ __forceinline__ u64 dpp_max_u64(u64 k) {
  int lo = (int)(u32)k, hi = (int)(u32)(k >> 32);
  int mlo = __builtin_amdgcn_update_dpp(lo, lo, CTRL, RM, 0xf, false);
  int mhi = __builtin_amdgcn_update_dpp(hi, hi, CTRL, RM, 0xf, false);
  u64 o = ((u64)(u32)mhi << 32) | (u32)mlo;
  return o > k ? o : k;
}

__device__ __forceinline__ u64 wave_max_u64(u64 k) {
  k = dpp_max_u64<0x111, 0xf>(k);   // row_shr:1
  k = dpp_max_u64<0x112, 0xf>(k);   // row_shr:2
  k = dpp_max_u64<0x114, 0xf>(k);   // row_shr:4
  k = dpp_max_u64<0x118, 0xf>(k);   // row_shr:8
  k = dpp_max_u64<0x142, 0xa>(k);   // row_bcast:15
  k = dpp_max_u64<0x143, 0xc>(k);   // row_bcast:31 -> lane63 = wave max
  return k;
}

__device__ __forceinline__ u64 read_lane_u64(u64 k, int lane) {
  u32 lo = (u32)__builtin_amdgcn_readlane((int)(u32)k, lane);
  u32 hi = (u32)__builtin_amdgcn_readlane((int)(u32)(k >> 32), lane);
  return ((u64)hi << 32) | lo;
}

struct FpsSmem {                    // FPS producer state
  u64 sred[2][8];                   // parity-buffered -> 1 barrier/step
  int s_centers[NG];
};
struct WkSmem {                     // ball-query worker state (512-thread tiling)
  u64 masks[256];                   // per-64-chunk in-radius bitmasks
  u32 scnt[256];
  u32 spre[256];
  u32 swsum[8];
  float candE[UPK];
  int   candI[UPK];
  int   s_T, s_pl;
  int   s_win[GS];
  u64   s_cc[2];                    // published center broadcast
};
union SmemU { FpsSmem f; WkSmem w; };
// pad forces LDS > 80 KiB -> hard 1 block/CU -> 256 blocks all co-resident
struct Smem { SmemU u; char pad[81920]; };

__device__ __forceinline__ void publish_center(u64* __restrict__ cb,
                                               float* __restrict__ out,
                                               int b, int w, float4 q) {
  u64 lo = ((u64)__float_as_uint(q.y) << 32) | __float_as_uint(q.x);
  u64 hi = ((u64)__float_as_uint(q.w) << 32) | __float_as_uint(q.z);
  __hip_atomic_store(&cb[2 * w],     lo, __ATOMIC_RELAXED, __HIP_MEMORY_SCOPE_AGENT);
  __hip_atomic_store(&cb[2 * w + 1], hi, __ATOMIC_RELAXED, __HIP_MEMORY_SCOPE_AGENT);
  if (w < CTX) ((float4*)(out + OFF_CENTERS))[b * CTX + w] = q;
}

#define FPS_T 512
#define PPT   (NP / FPS_T)   // 32 points per thread

__global__ __launch_bounds__(FPS_T)
__attribute__((amdgpu_waves_per_eu(2, 2)))
void fused_kernel(const float4* __restrict__ pts, const int* __restrict__ lengths,
                  u64* __restrict__ cws, int* __restrict__ group_len,
                  float* __restrict__ out)
{
  __shared__ Smem sm;
  const int blk  = blockIdx.x;
  const int tid  = threadIdx.x;
  const int lane = tid & 63;
  const int wave = tid >> 6;

  if (blk < NB) {
    // ------------------- FPS producer (R12 core, unchanged math) ------------
    FpsSmem& F = sm.u.f;
    const int b = blk;
    const float4* p = pts + (size_t)b * NP;
    const int len = lengths[b];
    u64* cb = cws + (size_t)b * NG * 2;

    const float4 q0 = p[0];
    float px[PPT], py[PPT], pz[PPT], mind[PPT];
#pragma unroll
    for (int j = 0; j < PPT; j++) {
      int i = tid + j * FPS_T;          // strided ownership -> coalesced loads
      float4 q = p[i];
      if (i >= len) q = q0;             // invalid -> alias of p[0]
      px[j] = q.x; py[j] = q.y; pz[j] = q.z;
      mind[j] = 1e10f;
    }
    if (tid == 0) F.s_centers[0] = 0;   // start index = 0

    int last = 0;
    for (int it = 1; it < NG; it++) {
      float4 lp = p[last];              // uniform -> scalar load, L2-served
      float tmax = -1.0f; int tj = 0;
#pragma unroll
      for (int j = 0; j < PPT; j++) {
        float d = dist2(px[j], py[j], pz[j], lp.x, lp.y, lp.z);
        float m = fminf(mind[j], d);
        mind[j] = m;
        bool c = m > tmax;              // strict > keeps earliest j
        tmax = c ? m : tmax;
        tj   = c ? j : tj;
      }
      int gidx = tid + (tj << 9);       // = global point index
      u64 key = ((u64)__float_as_uint(tmax) << 32) | (u32)(~gidx);
      key = wave_max_u64(key);          // lane 63 = wave winner
      u64 wkey = read_lane_u64(key, 63);
      if (lane == 0) F.sred[it & 1][wave] = wkey;
      __syncthreads();                  // single barrier per iteration
      u64 k2 = F.sred[it & 1][lane & 7];
      k2 = dpp_max_u64<0x111, 0xf>(k2);
      k2 = dpp_max_u64<0x112, 0xf>(k2);
      k2 = dpp_max_u64<0x114, 0xf>(k2); // lane7 = max of slots 0..7
      u64 bk = read_lane_u64(k2, 7);
      last = (int)(~(u32)bk) & (NP - 1);
      if (tid == 0) F.s_centers[it] = last;
      // Incremental publish: window [it-PUB, it-1], one center per lane.
      // Fire-and-forget atomics; wave0's ~400cy stall absorbed by next barrier.
      if ((it & (PUB - 1)) == 0 && tid < PUB) {
        int w = it - PUB + tid;
        int ci = F.s_centers[w] & (NP - 1);
        publish_center(cb, out, b, w, p[ci]);
      }
    }
    __syncthreads();
    if (tid < PUB) {                    // tail window 480..511
      int w = NG - PUB + tid;
      int ci = F.s_centers[w] & (NP - 1);
      publish_center(cb, out, b, w, p[ci]);
    }
    return;
  }

  // ------------------- ball-query consumer (512-thread tiling) --------------
  WkSmem& S = sm.u.w;
  const int b  = blk & (NB - 1);        // same XCD as fps block b
  const int wi = (blk >> 3) - 1;        // 0..30
  const float4* p = pts + (size_t)b * NP;
  const int len = lengths[b];
  u64* cb = cws + (size_t)b * NG * 2;

  for (int g = wi; g < NG; g += NWK) {
    if (tid == 0) {                     // sentinel spin; each word self-validates
      u64 lo, hi;
      while ((lo = __hip_atomic_load(&cb[2 * g], __ATOMIC_RELAXED,
                                     __HIP_MEMORY_SCOPE_AGENT)) == SENT)
        __builtin_amdgcn_s_sleep(8);
      while ((hi = __hip_atomic_load(&cb[2 * g + 1], __ATOMIC_RELAXED,
                                     __HIP_MEMORY_SCOPE_AGENT)) == SENT)
        __builtin_amdgcn_s_sleep(1);
      S.s_cc[0] = lo; S.s_cc[1] = hi;
    }
    __syncthreads();
    const float cx = __uint_as_float((u32)S.s_cc[0]);
    const float cy = __uint_as_float((u32)(S.s_cc[0] >> 32));
    const float cz = __uint_as_float((u32)S.s_cc[1]);

    if (g >= CTX) {                     // count-only: is this group full?
      u32 c = 0;
      for (int step = 0; step < 32; step++) {
        int i = step * 512 + tid;
        if (i < len) {
          float4 q = p[i];
          float d = dist2(cx, cy, cz, q.x, q.y, q.z);
          c += (d < 0.25f) ? 1u : 0u;
        }
      }
#pragma unroll
      for (int off = 32; off; off >>= 1) c += __shfl_down(c, (unsigned)off, 64);
      if (lane == 0) S.swsum[wave] = c;
      __syncthreads();
      if (tid == 0) {
        u32 total = 0;
#pragma unroll
        for (int w = 0; w < 8; w++) total += S.swsum[w];
        if (total >= GS) atomicAdd(&group_len[b], 1);
      }
      __syncthreads();                  // task-end barrier (LDS reuse safety)
      continue;
    }

    // Pass 1: in-radius flags, index order preserved via ballot
    for (int step = 0; step < 32; step++) {
      int i = step * 512 + tid;         // chunk = step*8 + wave, bit = lane
      bool flag = false;
      if (i < len) {
        float4 q = p[i];
        float d = dist2(cx, cy, cz, q.x, q.y, q.z);
        flag = d < 0.25f;               // radius^2, strict <
      }
      u64 m = __ballot(flag);
      if (lane == 0) S.masks[step * 8 + wave] = m;
    }
    __syncthreads();

    // Prefix scan over 256 chunk counts on the first 4 waves (identical math
    // to the standalone 256-thread kernel; integer-exact)
    u32 cnt = 0, sc = 0;
    if (tid < 256) {
      cnt = (u32)__popcll(S.masks[tid]);
      sc = cnt;
#pragma unroll
      for (int off = 1; off < 64; off <<= 1) {
        u32 o = __shfl_up(sc, (unsigned)off, 64);
        if (lane >= off) sc += o;
      }
      if (lane == 63) S.swsum[wave] = sc;
    }
    __syncthreads();
    const u32 total = S.swsum[0] + S.swsum[1] + S.swsum[2] + S.swsum[3];
    if (tid < 256) {
      u32 woff = 0;
#pragma unroll
      for (int w = 0; w < 4; w++) woff += (w < wave) ? S.swsum[w] : 0u;
      u32 incl = sc + woff;             // block-inclusive prefix for chunk tid
      S.scnt[tid] = cnt;
      S.spre[tid] = incl;
      // Cap index T: index of the (UPK-1)-ranked in-radius point
      if (total > UPK) {
        u32 ex = incl - cnt;
        if (ex <= (UPK - 1) && incl > (UPK - 1)) {    // exactly one thread
          u32 r = (UPK - 1) - ex;
          u64 m = S.masks[tid];
          for (u32 k = 0; k < r; k++) m &= m - 1;
          S.s_T = tid * 64 + ((int)__ffsll((unsigned long long)m) - 1);
        }
      } else if (tid == 0) S.s_T = NP - 1;
    }
    __syncthreads();                    // covers spre/scnt/s_T
    const int T = S.s_T;

    // Pass 2: compact (energy, idx) of candidates into LDS at exact rank
    for (int step = 0; step < 32; step++) {
      int i  = step * 512 + tid;
      int ch = step * 8 + wave;
      u64 m = S.masks[ch];
      if (((m >> lane) & 1ull) && i <= T) {
        u32 pos = ((S.spre[ch] - S.scnt[ch]) +
                   (u32)__popcll(m & ((1ull << lane) - 1ull))) & (UPK - 1);
        S.candE[pos] = ((const float*)p)[i * 4 + 3];   // energy channel
        S.candI[pos] = i;
      }
    }
    __syncthreads();

    const int ncand = (int)(total < UPK ? total : UPK);

    // Top-32 by (energy desc, pos asc): single wave, barrier-free rounds
    if (wave == 0) {
      u64 k[8];
#pragma unroll
      for (int t = 0; t < 8; t++) {
        int ci = lane + t * 64;
        k[t] = (ci < ncand) ? (((u64)fkey(S.candE[ci]) << 32) | (u32)(~ci)) : 0ull;
      }
      int pl = 0;
      for (int r = 0; r < GS; r++) {
        u64 bm = k[0];
#pragma unroll
        for (int t = 1; t < 8; t++) if (k[t] > bm) bm = k[t];
#pragma unroll
        for (int off = 32; off; off >>= 1) {
          u64 o = __shfl_xor(bm, (unsigned)off, 64);
          if (o > bm) bm = o;
        }
        if (bm == 0) break;             // wave-uniform: no candidates left
        int pos = (int)(~(u32)bm) & (UPK - 1);
        if (lane == 0) S.s_win[r] = S.candI[pos];
        int ol = pos & 63, ot = pos >> 6;
#pragma unroll
        for (int t = 0; t < 8; t++)     // kill winner (owner = lane ol, slot ot)
          if (t == ot && lane == ol) k[t] = 0;
        pl = r + 1;
      }
      if (lane == 0) {
        int f0 = (pl > 0) ? S.s_win[0] : 0;  // fill_empty_indices
        for (int r = pl; r < GS; r++) S.s_win[r] = f0;
        S.s_pl = pl;
      }
    }
    __syncthreads();

    const int base = b * CTX + g;
    if (tid < GS) {
      int fi = S.s_win[tid] & (NP - 1);
      float4 q = p[fi];
      ((float4*)out)[base * GS + tid] = q;
      out[OFF_PMASK + base * GS + tid] = (tid < S.s_pl) ? 1.0f : 0.0f;
    }
    if (tid == 0 && total >= GS) atomicAdd(&group_len[b], 1);
    __syncthreads();                    // task-end barrier (LDS reuse safety)
  }
}

// ---------------------------------------------------------------------------
// Init: sentinel the center mailboxes + zero group_len (stream-ordered before
// the fused kernel; removes the old producer-side group_len init, which would
// now race with worker atomicAdds).
// ---------------------------------------------------------------------------
__global__ void init_kernel(u64* __restrict__ cws, int* __restrict__ group_len)
{
  int i = blockIdx.x * blockDim.x + threadIdx.x;
  if (i < NB * NG * 2)
    __hip_atomic_store(&cws[i], SENT, __ATOMIC_RELAXED, __HIP_MEMORY_SCOPE_AGENT);
  if (i < NB) group_len[i] = 0;
}

// ---------------------------------------------------------------------------
// Embedding mask from full-group counts (needs final group_len -> after fused)
// ---------------------------------------------------------------------------
__global__ void emb_kernel(const int* __restrict__ group_len,
                           float* __restrict__ out)
{
  int i = blockIdx.x * blockDim.x + threadIdx.x;
  if (i < NB * CTX) {
    int b = i >> 8;
    int g = i & 255;
    out[OFF_EMB + i] = (g < group_len[b]) ? 1.0f : 0.0f;
  }
}

extern "C" void kernel_launch(void* const* d_in, const int* in_sizes, int n_in,
                              void* d_out, int out_size, void* d_ws, size_t ws_size,
                              hipStream_t stream)
{
  const float4* pts     = (const float4*)d_in[0];   // f32 (B,N,4)
  const int*    lengths = (const int*)d_in[1];
  float* out = (float*)d_out;

  u64* cws       = (u64*)d_ws;                      // 8*512*16 B = 64 KB mailboxes
  int* group_len = (int*)((char*)d_ws + (size_t)NB * NG * sizeof(float4));

  init_kernel<<<(NB * NG * 2 + 255) / 256, 256, 0, stream>>>(cws, group_len);
  fused_kernel<<<NB + NB * NWK, FPS_T, 0, stream>>>(pts, lengths, cws, group_len, out);
  emb_kernel<<<(NB * CTX + 255) / 256, 256, 0, stream>>>(group_len, out);
}

// Round 2
// 681.106 us; speedup vs baseline: 1.0777x; 1.0382x over previous
//
#include <hip/hip_runtime.h>
#include <stdint.h>

// Problem constants (match reference)
#define NB   8
#define NP   16384
#define NG   512      // NUM_GROUPS
#define GS   32       // GROUP_SIZE
#define UPK  512      // UPSCALE_K
#define CTX  256      // CONTEXT

// float32 output layout (flat element offsets):
// groups (8,256,32,4) | centers (8,256,4) | emb_mask (8,256) | point_mask (8,256,32)
#define OFF_CENTERS (NB*CTX*GS*4)            // 262144
#define OFF_EMB     (OFF_CENTERS + NB*CTX*4) // 270336
#define OFF_PMASK   (OFF_EMB + NB*CTX)       // 272384

typedef unsigned long long u64;
typedef unsigned int u32;

// R17: index-only publish. R16's window publish put a 32-lane scattered
// gather + 64 atomic stores on wave 0 every 32 iterations (barrier waits on
// wave 0), and released centers in bursts of 32 -> all 31 same-XCD workers
// fired at once (~3 TB/s L2 burst) inflating the producer's dependent
// p[last] load latency. Now: tid0 stores the center INDEX (u32, relaxed,
// agent scope) once per iteration, right after `last` is known — hidden
// under the next ~1500-cyc distance loop (pre-barrier vmcnt drain already
// waits on the consumed p[last] load, so the store retires for free).
// Workers fetch p[ci] themselves (one L2 hit) and write the centers output.
// Sentinel 0xFFFFFFFF self-validates (indices < 16384) -> no fences anywhere
// on the producer's critical path.
// Deadlock safety unchanged: grid == 256 blocks, ~88 KiB LDS -> 1 block/CU
// -> all co-resident; workers wait only on producer publishes; producers
// wait on nothing external.
#define SENT32 0xFFFFFFFFu
#define NWK    31     // worker blocks per batch (8 + 8*31 = 256 = #CUs)

// Monotonic float->uint key (full-range; needed for energies which can be <0)
__device__ __forceinline__ u32 fkey(float f) {
  union { float f; u32 u; } v; v.f = f;
  u32 s = v.u;
  return s ^ ((s & 0x80000000u) ? 0xFFFFFFFFu : 0x80000000u);
}

// Strictly-unfused f32 squared distance, op order = np: ((dx*dx+dy*dy)+dz*dz).
// _rn intrinsics forbid FMA contraction (hipcc defaults -ffp-contract=fast).
// NOTE (R15 post-mortem): the algebraic FMA form broke selection (absmax 2.26).
// This unfused difference form is load-bearing.
__device__ __forceinline__ float dist2(float ax, float ay, float az,
                                       float bx, float by, float bz) {
  float dx = __fsub_rn(ax, bx);
  float dy = __fsub_rn(ay, by);
  float dz = __fsub_rn(az, bz);
  return __fadd_rn(__fadd_rn(__fmul_rn(dx, dx), __fmul_rn(dy, dy)),
                   __fmul_rn(dz, dz));
}

// u64 max-combine with a DPP-moved copy (bound_ctrl=false keeps own value
// for invalid sources -> max no-op there). Proven since R8 (absmax 0).
template<int CTRL, int RM>
__device__ __forceinline__ u64 dpp_max_u64(u64 k) {
  int lo = (int)(u32)k, hi = (int)(u32)(k >> 32);
  int mlo = __builtin_amdgcn_update_dpp(lo, lo, CTRL, RM, 0xf, false);
  int mhi = __builtin_amdgcn_update_dpp(hi, hi, CTRL, RM, 0xf, false);
  u64 o = ((u64)(u32)mhi << 32) | (u32)mlo;
  return o > k ? o : k;
}

__device__ __forceinline__ u64 wave_max_u64(u64 k) {
  k = dpp_max_u64<0x111, 0xf>(k);   // row_shr:1
  k = dpp_max_u64<0x112, 0xf>(k);   // row_shr:2
  k = dpp_max_u64<0x114, 0xf>(k);   // row_shr:4
  k = dpp_max_u64<0x118, 0xf>(k);   // row_shr:8
  k = dpp_max_u64<0x142, 0xa>(k);   // row_bcast:15
  k = dpp_max_u64<0x143, 0xc>(k);   // row_bcast:31 -> lane63 = wave max
  return k;
}

__device__ __forceinline__ u64 read_lane_u64(u64 k, int lane) {
  u32 lo = (u32)__builtin_amdgcn_readlane((int)(u32)k, lane);
  u32 hi = (u32)__builtin_amdgcn_readlane((int)(u32)(k >> 32), lane);
  return ((u64)hi << 32) | lo;
}

struct FpsSmem {                    // FPS producer state
  u64 sred[2][8];                   // parity-buffered -> 1 barrier/step
};
struct WkSmem {                     // ball-query worker state (512-thread tiling)
  u64 masks[256];                   // per-64-chunk in-radius bitmasks
  u32 scnt[256];
  u32 spre[256];
  u32 swsum[8];
  float candE[UPK];
  int   candI[UPK];
  int   s_T, s_pl;
  int   s_fin, s_gl;                // finisher flag + final group_len broadcast
  int   s_win[GS];
  float4 s_cc;                      // fetched center broadcast
};
union SmemU { FpsSmem f; WkSmem w; };
// pad forces LDS > 80 KiB -> hard 1 block/CU -> 256 blocks all co-resident
struct Smem { SmemU u; char pad[81920]; };

#define FPS_T 512
#define PPT   (NP / FPS_T)   // 32 points per thread

__global__ __launch_bounds__(FPS_T)
__attribute__((amdgpu_waves_per_eu(2, 2)))
void fused_kernel(const float4* __restrict__ pts, const int* __restrict__ lengths,
                  u32* __restrict__ cws, int* __restrict__ group_len,
                  int* __restrict__ wdone, float* __restrict__ out)
{
  __shared__ Smem sm;
  const int blk  = blockIdx.x;
  const int tid  = threadIdx.x;
  const int lane = tid & 63;
  const int wave = tid >> 6;

  if (blk < NB) {
    // ------------------- FPS producer (R12 core, unchanged math) ------------
    FpsSmem& F = sm.u.f;
    const int b = blk;
    const float4* p = pts + (size_t)b * NP;
    const int len = lengths[b];
    u32* cb = cws + (size_t)b * NG;
    if (tid == 0)                       // center 0 = point 0, publish ASAP
      __hip_atomic_store(&cb[0], 0u, __ATOMIC_RELAXED, __HIP_MEMORY_SCOPE_AGENT);

    const float4 q0 = p[0];
    float px[PPT], py[PPT], pz[PPT], mind[PPT];
#pragma unroll
    for (int j = 0; j < PPT; j++) {
      int i = tid + j * FPS_T;          // strided ownership -> coalesced loads
      float4 q = p[i];
      if (i >= len) q = q0;             // invalid -> alias of p[0]
      px[j] = q.x; py[j] = q.y; pz[j] = q.z;
      mind[j] = 1e10f;
    }

    int last = 0;
    for (int it = 1; it < NG; it++) {
      float4 lp = p[last];              // uniform -> scalar load, L2-served
      float tmax = -1.0f; int tj = 0;
#pragma unroll
      for (int j = 0; j < PPT; j++) {
        float d = dist2(px[j], py[j], pz[j], lp.x, lp.y, lp.z);
        float m = fminf(mind[j], d);
        mind[j] = m;
        bool c = m > tmax;              // strict > keeps earliest j
        tmax = c ? m : tmax;
        tj   = c ? j : tj;
      }
      int gidx = tid + (tj << 9);       // = global point index
      u64 key = ((u64)__float_as_uint(tmax) << 32) | (u32)(~gidx);
      key = wave_max_u64(key);          // lane 63 = wave winner
      u64 wkey = read_lane_u64(key, 63);
      if (lane == 0) F.sred[it & 1][wave] = wkey;
      __syncthreads();                  // single barrier per iteration
      u64 k2 = F.sred[it & 1][lane & 7];
      k2 = dpp_max_u64<0x111, 0xf>(k2);
      k2 = dpp_max_u64<0x112, 0xf>(k2);
      k2 = dpp_max_u64<0x114, 0xf>(k2); // lane7 = max of slots 0..7
      u64 bk = read_lane_u64(k2, 7);
      last = (int)(~(u32)bk) & (NP - 1);
      // Per-iteration index publish: one fire-and-forget u32 store by tid0,
      // retired under the next iteration's distance loop. Zero barrier cost.
      if (tid == 0)
        __hip_atomic_store(&cb[it], (u32)last, __ATOMIC_RELAXED,
                           __HIP_MEMORY_SCOPE_AGENT);
    }
    return;
  }

  // ------------------- ball-query consumer (512-thread tiling) --------------
  WkSmem& S = sm.u.w;
  const int b  = blk & (NB - 1);        // same XCD as fps block b
  const int wi = (blk >> 3) - 1;        // 0..30
  const float4* p = pts + (size_t)b * NP;
  const int len = lengths[b];
  u32* cb = cws + (size_t)b * NG;

  for (int g = wi; g < NG; g += NWK) {
    if (tid == 0) {                     // sentinel spin; index self-validates
      u32 ci;
      while ((ci = __hip_atomic_load(&cb[g], __ATOMIC_RELAXED,
                                     __HIP_MEMORY_SCOPE_AGENT)) == SENT32)
        __builtin_amdgcn_s_sleep(8);
      float4 q = p[ci];                 // L2-hot (same-XCD point data)
      S.s_cc = q;
      if (g < CTX)                      // workers own the centers output now
        ((float4*)(out + OFF_CENTERS))[b * CTX + g] = q;
    }
    __syncthreads();
    const float cx = S.s_cc.x, cy = S.s_cc.y, cz = S.s_cc.z;

    if (g >= CTX) {                     // count-only: is this group full?
      // Wave-uniform early exit: c = running popc(ballot) per 512-pt step.
      // Any wave reaching GS implies total >= GS; if no wave exits early the
      // sum is exact -> decision (sum >= GS) is exact either way.
      u32 c = 0;
      for (int step = 0; step < 32; step++) {
        int i = step * 512 + tid;
        bool flag = false;
        if (i < len) {
          float4 q = p[i];
          float d = dist2(cx, cy, cz, q.x, q.y, q.z);
          flag = d < 0.25f;
        }
        c += (u32)__popcll(__ballot(flag));
        if (c >= GS) break;             // c is wave-uniform
      }
      if (lane == 0) S.swsum[wave] = c;
      __syncthreads();
      if (tid == 0) {
        u32 total = 0;
#pragma unroll
        for (int w = 0; w < 8; w++) total += S.swsum[w];
        if (total >= GS) atomicAdd(&group_len[b], 1);
      }
      __syncthreads();                  // task-end barrier (LDS reuse safety)
      continue;
    }

    // Pass 1: in-radius flags, index order preserved via ballot
    for (int step = 0; step < 32; step++) {
      int i = step * 512 + tid;         // chunk = step*8 + wave, bit = lane
      bool flag = false;
      if (i < len) {
        float4 q = p[i];
        float d = dist2(cx, cy, cz, q.x, q.y, q.z);
        flag = d < 0.25f;               // radius^2, strict <
      }
      u64 m = __ballot(flag);
      if (lane == 0) S.masks[step * 8 + wave] = m;
    }
    __syncthreads();

    // Prefix scan over 256 chunk counts on the first 4 waves (identical math
    // to the standalone 256-thread kernel; integer-exact)
    u32 cnt = 0, sc = 0;
    if (tid < 256) {
      cnt = (u32)__popcll(S.masks[tid]);
      sc = cnt;
#pragma unroll
      for (int off = 1; off < 64; off <<= 1) {
        u32 o = __shfl_up(sc, (unsigned)off, 64);
        if (lane >= off) sc += o;
      }
      if (lane == 63) S.swsum[wave] = sc;
    }
    __syncthreads();
    const u32 total = S.swsum[0] + S.swsum[1] + S.swsum[2] + S.swsum[3];
    if (tid < 256) {
      u32 woff = 0;
#pragma unroll
      for (int w = 0; w < 4; w++) woff += (w < wave) ? S.swsum[w] : 0u;
      u32 incl = sc + woff;             // block-inclusive prefix for chunk tid
      S.scnt[tid] = cnt;
      S.spre[tid] = incl;
      // Cap index T: index of the (UPK-1)-ranked in-radius point
      if (total > UPK) {
        u32 ex = incl - cnt;
        if (ex <= (UPK - 1) && incl > (UPK - 1)) {    // exactly one thread
          u32 r = (UPK - 1) - ex;
          u64 m = S.masks[tid];
          for (u32 k = 0; k < r; k++) m &= m - 1;
          S.s_T = tid * 64 + ((int)__ffsll((unsigned long long)m) - 1);
        }
      } else if (tid == 0) S.s_T = NP - 1;
    }
    __syncthreads();                    // covers spre/scnt/s_T
    const int T = S.s_T;

    // Pass 2: compact (energy, idx) of candidates into LDS at exact rank
    for (int step = 0; step < 32; step++) {
      int i  = step * 512 + tid;
      int ch = step * 8 + wave;
      u64 m = S.masks[ch];
      if (((m >> lane) & 1ull) && i <= T) {
        u32 pos = ((S.spre[ch] - S.scnt[ch]) +
                   (u32)__popcll(m & ((1ull << lane) - 1ull))) & (UPK - 1);
        S.candE[pos] = ((const float*)p)[i * 4 + 3];   // energy channel
        S.candI[pos] = i;
      }
    }
    __syncthreads();

    const int ncand = (int)(total < UPK ? total : UPK);

    // Top-32 by (energy desc, pos asc): single wave, barrier-free rounds
    if (wave == 0) {
      u64 k[8];
#pragma unroll
      for (int t = 0; t < 8; t++) {
        int ci = lane + t * 64;
        k[t] = (ci < ncand) ? (((u64)fkey(S.candE[ci]) << 32) | (u32)(~ci)) : 0ull;
      }
      int pl = 0;
      for (int r = 0; r < GS; r++) {
        u64 bm = k[0];
#pragma unroll
        for (int t = 1; t < 8; t++) if (k[t] > bm) bm = k[t];
#pragma unroll
        for (int off = 32; off; off >>= 1) {
          u64 o = __shfl_xor(bm, (unsigned)off, 64);
          if (o > bm) bm = o;
        }
        if (bm == 0) break;             // wave-uniform: no candidates left
        int pos = (int)(~(u32)bm) & (UPK - 1);
        if (lane == 0) S.s_win[r] = S.candI[pos];
        int ol = pos & 63, ot = pos >> 6;
#pragma unroll
        for (int t = 0; t < 8; t++)     // kill winner (owner = lane ol, slot ot)
          if (t == ot && lane == ol) k[t] = 0;
        pl = r + 1;
      }
      if (lane == 0) {
        int f0 = (pl > 0) ? S.s_win[0] : 0;  // fill_empty_indices
        for (int r = pl; r < GS; r++) S.s_win[r] = f0;
        S.s_pl = pl;
      }
    }
    __syncthreads();

    const int base = b * CTX + g;
    if (tid < GS) {
      int fi = S.s_win[tid] & (NP - 1);
      float4 q = p[fi];
      ((float4*)out)[base * GS + tid] = q;
      out[OFF_PMASK + base * GS + tid] = (tid < S.s_pl) ? 1.0f : 0.0f;
    }
    if (tid == 0 && total >= GS) atomicAdd(&group_len[b], 1);
    __syncthreads();                    // task-end barrier (LDS reuse safety)
  }

  // Folded emb_kernel: last finisher per batch writes the embedding mask.
  // acq_rel RMW chain on wdone[b] makes every worker's group_len adds
  // visible to the finisher (release sequence through the RMW chain).
  if (tid == 0) {
    int old = __hip_atomic_fetch_add(&wdone[b], 1, __ATOMIC_ACQ_REL,
                                     __HIP_MEMORY_SCOPE_AGENT);
    int fin = (old == NWK - 1) ? 1 : 0;
    S.s_fin = fin;
    S.s_gl = fin ? __hip_atomic_load(&group_len[b], __ATOMIC_RELAXED,
                                     __HIP_MEMORY_SCOPE_AGENT) : 0;
  }
  __syncthreads();
  if (S.s_fin && tid < CTX)
    out[OFF_EMB + b * CTX + tid] = (tid < S.s_gl) ? 1.0f : 0.0f;
}

// ---------------------------------------------------------------------------
// Init: sentinel the index mailboxes + zero group_len / done counters
// (stream-ordered before the fused kernel).
// ---------------------------------------------------------------------------
__global__ void init_kernel(u32* __restrict__ cws, int* __restrict__ group_len,
                            int* __restrict__ wdone)
{
  int i = blockIdx.x * blockDim.x + threadIdx.x;
  if (i < NB * NG)
    __hip_atomic_store(&cws[i], SENT32, __ATOMIC_RELAXED, __HIP_MEMORY_SCOPE_AGENT);
  if (i < NB) { group_len[i] = 0; wdone[i] = 0; }
}

extern "C" void kernel_launch(void* const* d_in, const int* in_sizes, int n_in,
                              void* d_out, int out_size, void* d_ws, size_t ws_size,
                              hipStream_t stream)
{
  const float4* pts     = (const float4*)d_in[0];   // f32 (B,N,4)
  const int*    lengths = (const int*)d_in[1];
  float* out = (float*)d_out;

  u32* cws       = (u32*)d_ws;                      // 8*512*4 B = 16 KB mailboxes
  int* group_len = (int*)(cws + NB * NG);
  int* wdone     = group_len + NB;

  init_kernel<<<(NB * NG + 255) / 256, 256, 0, stream>>>(cws, group_len, wdone);
  fused_kernel<<<NB + NB * NWK, FPS_T, 0, stream>>>(pts, lengths, cws, group_len,
                                                    wdone, out);
}